// Round 1
// baseline (640.006 us; speedup 1.0000x reference)
//
#include <hip/hip_runtime.h>

// Model_65678639890860: sequential LSTM-ish recurrence, VEL=6, U=4, seqlen=4096.
// Pure latency problem: one wave64, all weights in registers, DPP-only
// cross-lane traffic. Lane = v*4+u (24 active lanes); junk lanes clamped to
// lane 23's data (bounded dynamics, no NaN risk, quad-local DPP keeps them
// isolated from the real quads 0..5).

#define L2E 1.4426950408889634f

__device__ __forceinline__ float rcp_f(float x) {
#if __has_builtin(__builtin_amdgcn_rcpf)
    return __builtin_amdgcn_rcpf(x);       // v_rcp_f32, ~1 ulp — fine for 2e-2 threshold
#else
    return 1.0f / x;
#endif
}

__device__ __forceinline__ float exp2_f(float x) {
#if __has_builtin(__builtin_amdgcn_exp2f)
    return __builtin_amdgcn_exp2f(x);      // v_exp_f32 (2^x)
#else
    return exp2f(x);
#endif
}

template <int CTRL>
__device__ __forceinline__ float dpp_f(float x) {
    // quad_perm DPP move: full-rate VALU, quad-local. CTRL = pat[0]|pat[1]<<2|...
    return __int_as_float(
        __builtin_amdgcn_mov_dpp(__float_as_int(x), CTRL, 0xF, 0xF, true));
}

__global__ __launch_bounds__(64) void lstm_seq(
    const float* __restrict__ vel, const float* __restrict__ h0,
    const float* __restrict__ c0,
    const float* __restrict__ Wix, const float* __restrict__ Wih, const float* __restrict__ bi,
    const float* __restrict__ Wfx, const float* __restrict__ Wfh, const float* __restrict__ bf,
    const float* __restrict__ Wox, const float* __restrict__ Woh, const float* __restrict__ bo,
    const float* __restrict__ Wgx, const float* __restrict__ Wgh, const float* __restrict__ bg,
    const float* __restrict__ linear, const float* __restrict__ bl,
    const int* __restrict__ seqlen, float* __restrict__ out)
{
    const int lane = threadIdx.x;
    const int l = lane < 24 ? lane : 23;   // clamp junk lanes to valid data
    const int v = l >> 2;
    const int u = l & 3;

    // Gate formula (from reference):
    //   arg_g[v,u] = Wxg[u,v]*x[v] + sum_k Whg[v*4+u,k]*h[v,k] + bg[v,u]
    const float wxi = Wix[u * 6 + v], wxf = Wfx[u * 6 + v];
    const float wxo = Wox[u * 6 + v], wxg = Wgx[u * 6 + v];
    const float bii = bi[l], bff = bf[l], boo = bo[l], bgg = bg[l];
    float whi[4], whf[4], who[4], whg[4];
#pragma unroll
    for (int k = 0; k < 4; ++k) {
        whi[k] = Wih[l * 4 + k];
        whf[k] = Wfh[l * 4 + k];
        who[k] = Woh[l * 4 + k];
        whg[k] = Wgh[l * 4 + k];
    }
    const float lin = linear[l];
    const float blv = bl[v];

    float h = h0[l];
    float c = c0[l];
    float x = vel[v];
    const int T = seqlen[0];

#pragma unroll 2
    for (int t = 0; t < T; ++t) {
        // all-gather h[v,0..3] within the quad (u is low 2 lane bits)
        const float hb0 = dpp_f<0x00>(h);   // quad_perm [0,0,0,0]
        const float hb1 = dpp_f<0x55>(h);   // [1,1,1,1]
        const float hb2 = dpp_f<0xAA>(h);   // [2,2,2,2]
        const float hb3 = dpp_f<0xFF>(h);   // [3,3,3,3]

        float ai = fmaf(whi[0], hb0, bii);
        ai = fmaf(whi[1], hb1, ai); ai = fmaf(whi[2], hb2, ai);
        ai = fmaf(whi[3], hb3, ai); ai = fmaf(wxi, x, ai);

        float af = fmaf(whf[0], hb0, bff);
        af = fmaf(whf[1], hb1, af); af = fmaf(whf[2], hb2, af);
        af = fmaf(whf[3], hb3, af); af = fmaf(wxf, x, af);

        float ao = fmaf(who[0], hb0, boo);
        ao = fmaf(who[1], hb1, ao); ao = fmaf(who[2], hb2, ao);
        ao = fmaf(who[3], hb3, ao); ao = fmaf(wxo, x, ao);

        float ag = fmaf(whg[0], hb0, bgg);
        ag = fmaf(whg[1], hb1, ag); ag = fmaf(whg[2], hb2, ag);
        ag = fmaf(whg[3], hb3, ag); ag = fmaf(wxg, x, ag);

        const float ei = exp2_f(ai * -L2E);
        const float ef = exp2_f(af * -L2E);
        const float eo = exp2_f(ao * -L2E);
        const float eg = exp2_f(ag * -L2E);

        // sigmoid(i)*sigmoid(g) = 1/((1+e_i)(1+e_g)); denominators >= 1, so
        // inf saturates to 0 correctly, no NaN path.
        const float ig = rcp_f((1.0f + ei) * (1.0f + eg));
        const float ft = rcp_f(1.0f + ef);
        c = fmaf(ft, c, ig);                       // c_new = f*c + i*cbar

        const float ec = exp2_f(c * -L2E);
        h = rcp_f((1.0f + eo) * (1.0f + ec));      // h_new = o * sigmoid(c_new)

        // out[v] = tanh(sum_u lin[v,u]*h[v,u] + bl[v]) — quad butterfly sum
        float m = lin * h;
        m += dpp_f<0xB1>(m);                       // quad_perm [1,0,3,2]
        m += dpp_f<0x4E>(m);                       // quad_perm [2,3,0,1]
        const float y = m + blv;
        const float ey = exp2_f(y * (2.0f * L2E));
        x = fmaf(-2.0f, rcp_f(1.0f + ey), 1.0f);   // tanh(y) = 1 - 2/(1+e^{2y})
    }

    if (lane < 24 && u == 0) out[v] = x;
}

extern "C" void kernel_launch(void* const* d_in, const int* in_sizes, int n_in,
                              void* d_out, int out_size, void* d_ws, size_t ws_size,
                              hipStream_t stream) {
    (void)in_sizes; (void)n_in; (void)out_size; (void)d_ws; (void)ws_size;
    lstm_seq<<<1, 64, 0, stream>>>(
        (const float*)d_in[0],  (const float*)d_in[1],  (const float*)d_in[2],
        (const float*)d_in[3],  (const float*)d_in[4],  (const float*)d_in[5],
        (const float*)d_in[6],  (const float*)d_in[7],  (const float*)d_in[8],
        (const float*)d_in[9],  (const float*)d_in[10], (const float*)d_in[11],
        (const float*)d_in[12], (const float*)d_in[13], (const float*)d_in[14],
        (const float*)d_in[15], (const float*)d_in[16],
        (const int*)d_in[17],   (float*)d_out);
}

// Round 2
// 501.043 us; speedup vs baseline: 1.2773x; 1.2773x over previous
//
#include <hip/hip_runtime.h>

// Model_65678639890860 R2: 48-lane gate-split LSTM recurrence.
// Lane layout: lane = v*8 + (gp ? 4+(3-u) : u);  gp0 = gates (i,f), gp1 = (g,o).
// gp1's u-order is mirrored so ROW_HALF_MIRROR (dpp 0x141) swaps the partner
// (v,u) between quads in one full-rate instruction. All weights pre-scaled by
// -log2(e) so gate dots feed v_exp_f32 directly; linear/bl pre-scaled by
// 2*log2(e) so the tanh exp needs no argument scaling; x is carried as
// ry = 1/(1+e^{2y}) and folded into the gate dot via fma(-2*wx, ry, wx).

#define L2E 1.4426950408889634f

__device__ __forceinline__ float rcp_f(float x) { return __builtin_amdgcn_rcpf(x); }
__device__ __forceinline__ float exp2_f(float x) { return __builtin_amdgcn_exp2f(x); }

template <int CTRL>
__device__ __forceinline__ float dpp_f(float x) {
    return __int_as_float(
        __builtin_amdgcn_mov_dpp(__float_as_int(x), CTRL, 0xF, 0xF, true));
}

__global__ __launch_bounds__(64) void lstm_seq(
    const float* __restrict__ vel, const float* __restrict__ h0,
    const float* __restrict__ c0,
    const float* __restrict__ Wix, const float* __restrict__ Wih, const float* __restrict__ bi,
    const float* __restrict__ Wfx, const float* __restrict__ Wfh, const float* __restrict__ bf,
    const float* __restrict__ Wox, const float* __restrict__ Woh, const float* __restrict__ bo,
    const float* __restrict__ Wgx, const float* __restrict__ Wgh, const float* __restrict__ bg,
    const float* __restrict__ linear, const float* __restrict__ bl,
    const int* __restrict__ seqlen, float* __restrict__ out)
{
    const int lane = threadIdx.x;
    const int lc = lane < 48 ? lane : (lane - 16);  // junk octets 6,7 mirror octets 4,5
    const int o  = lc & 7;
    const int gp = o >> 2;                 // 0: (i,f)   1: (g,o)
    const int u  = gp ? (3 - (o & 3)) : (o & 3);
    const int v  = lc >> 3;
    const int l24 = v * 4 + u;
    const bool isG0 = (gp == 0);

    // slot A = i (gp0) / g (gp1);  slot B = f (gp0) / o (gp1)
    const float* WhA = gp ? Wgh : Wih;  const float* WhB = gp ? Woh : Wfh;
    const float* WxA = gp ? Wgx : Wix;  const float* WxB = gp ? Wox : Wfx;
    const float* bA  = gp ? bg  : bi;   const float* bB  = gp ? bo  : bf;

    float wah[4], wbh[4];
#pragma unroll
    for (int k = 0; k < 4; ++k) {
        const int ke = gp ? (3 - k) : k;   // hb_k holds h[v, gp ? 3-k : k]
        wah[k] = -L2E * WhA[l24 * 4 + ke];
        wbh[k] = -L2E * WhB[l24 * 4 + ke];
    }
    const float ba   = -L2E * bA[l24];
    const float bb   = -L2E * bB[l24];
    const float wxa  = -L2E * WxA[u * 6 + v];
    const float wxb  = -L2E * WxB[u * 6 + v];
    const float wxa2 = -2.0f * wxa;
    const float wxb2 = -2.0f * wxb;
    const float lin  = 2.0f * L2E * linear[l24];
    const float blv  = 0.5f * L2E * bl[v];   // 2*L2E*bl / 4 (added on all 4 lanes)

    float h  = h0[l24];
    float c  = c0[l24];
    float ry = 0.5f * (1.0f - vel[v]);       // x = 1 - 2*ry
    const int T = seqlen[0];

#pragma unroll 4
    for (int t = 0; t < T; ++t) {
        // broadcast h across the quad (weights absorbed gp1's mirrored order)
        const float hb0 = dpp_f<0x00>(h);
        const float hb1 = dpp_f<0x55>(h);
        const float hb2 = dpp_f<0xAA>(h);
        const float hb3 = dpp_f<0xFF>(h);

        // x-contribution: wx * (1 - 2*ry)
        const float wxxa = fmaf(wxa2, ry, wxa);
        const float wxxb = fmaf(wxb2, ry, wxb);

        // two tree-structured 6-term dots (already scaled by -log2 e)
        const float pa = fmaf(wah[1], hb1, fmaf(wah[0], hb0, ba));
        const float qa = fmaf(wah[3], hb3, fmaf(wah[2], hb2, wxxa));
        const float a  = pa + qa;
        const float pb = fmaf(wbh[1], hb1, fmaf(wbh[0], hb0, bb));
        const float qb = fmaf(wbh[3], hb3, fmaf(wbh[2], hb2, wxxb));
        const float b  = pb + qb;

        const float da = 1.0f + exp2_f(a);   // gp0: 1+e_i   gp1: 1+e_g
        const float db = 1.0f + exp2_f(b);   // gp0: 1+e_f   gp1: 1+e_o

        const float da_m = dpp_f<0x141>(da); // partner quad's slot-A denom
        const float db_m = dpp_f<0x141>(db); // partner quad's slot-B denom

        const float ig   = rcp_f(da * da_m);        // sig(i)*sig(g), both quads
        const float denF = isG0 ? db : db_m;        // 1+e_f
        const float denO = isG0 ? db_m : db;        // 1+e_o
        const float ft   = rcp_f(denF);

        c = fmaf(ft, c, ig);                        // c = f*c + i*cbar
        const float dc = 1.0f + exp2_f(c * -L2E);
        h = rcp_f(denO * dc);                       // h = sig(o)*sig(c)

        // y' = 2*log2(e) * (sum_u lin*h + bl)  via quad butterfly
        float m = fmaf(lin, h, blv);
        m += dpp_f<0xB1>(m);
        m += dpp_f<0x4E>(m);
        const float ey = exp2_f(m);
        ry = rcp_f(1.0f + ey);                      // x = 1 - 2*ry = tanh(y)
    }

    if (lane < 48 && o == 0) out[v] = fmaf(-2.0f, ry, 1.0f);
}

extern "C" void kernel_launch(void* const* d_in, const int* in_sizes, int n_in,
                              void* d_out, int out_size, void* d_ws, size_t ws_size,
                              hipStream_t stream) {
    (void)in_sizes; (void)n_in; (void)out_size; (void)d_ws; (void)ws_size;
    lstm_seq<<<1, 64, 0, stream>>>(
        (const float*)d_in[0],  (const float*)d_in[1],  (const float*)d_in[2],
        (const float*)d_in[3],  (const float*)d_in[4],  (const float*)d_in[5],
        (const float*)d_in[6],  (const float*)d_in[7],  (const float*)d_in[8],
        (const float*)d_in[9],  (const float*)d_in[10], (const float*)d_in[11],
        (const float*)d_in[12], (const float*)d_in[13], (const float*)d_in[14],
        (const float*)d_in[15], (const float*)d_in[16],
        (const int*)d_in[17],   (float*)d_out);
}